// Round 13
// baseline (145.972 us; speedup 1.0000x reference)
//
#include <hip/hip_runtime.h>
#include <hip/hip_bf16.h>
#include <math.h>

#define DEVFN __device__ __forceinline__

typedef __attribute__((ext_vector_type(8))) __bf16 bf16x8;
typedef __attribute__((ext_vector_type(8))) short s16x8;
typedef __attribute__((ext_vector_type(4))) float f32x4;
typedef __attribute__((ext_vector_type(4))) unsigned int u32x4;

constexpr int Tt    = 2048;
constexpr int INt   = 128;
constexpr int Ht    = 256;
constexpr int OUTt  = 8;
constexpr int TT    = 64;           // time tile
constexpr int NTILE = 32;

union Frag {
  s16x8 s;
  bf16x8 b;
  u32x4 u;
};

DEVFN unsigned short f2bf(float f) {
  unsigned int u = __builtin_bit_cast(unsigned int, f);
  u += 0x7fffu + ((u >> 16) & 1u);   // round-to-nearest-even
  return (unsigned short)(u >> 16);
}

DEVFN unsigned int pack2(float lo, float hi) {
  return (unsigned int)f2bf(lo) | ((unsigned int)f2bf(hi) << 16);
}

__global__
__attribute__((amdgpu_flat_work_group_size(1024, 1024), amdgpu_waves_per_eu(4, 4)))
void sfnn_fused(
    const float* __restrict__ x, const float* __restrict__ Wb,
    const float* __restrict__ bb, const float* __restrict__ Wo,
    const float* __restrict__ bo, const float* __restrict__ tau_m,
    const float* __restrict__ tau_n, float* __restrict__ out)
{
  const int b    = blockIdx.x;
  const int tid  = threadIdx.x;
  const int lane = tid & 63;
  const int w    = tid >> 6;          // wave id 0..15
  const int l16  = lane & 15;
  const int lhi  = lane >> 4;
  const int sid  = tid - 512;         // stager index (waves 8-15)

  // LDS: 32KB Xb + 64KB DfT + 32KB Mb + 8KB WoT = 136KB  (r6 layout)
  __shared__ __align__(16) unsigned char  Xb[2][TT * 256];      // bf16 x, swizzled
  __shared__ __align__(16) float          DfT[Ht * TT];         // D^T f32 [h][t], swz
  __shared__ __align__(16) unsigned short Mb[TT * Ht];          // m bf16 [t][p], swz
  __shared__ __align__(16) unsigned short WoT[16 * Ht];         // Wo^T bf16 [j][p], swz

  // ---- stage WoT with PERMUTED k-axis: column p holds channel
  // inv_p(p) = (p&1)*128 + (p>>1)  (so scan's (ch, ch+128) pair lands adjacent)
  {
    const int j  = w;
    const int k0 = 4 * (tid & 63);
    float v0 = 0.f, v1 = 0.f, v2 = 0.f, v3 = 0.f;
    if (j < OUTt) {
      v0 = Wo[(((k0 + 0) & 1) * 128 + ((k0 + 0) >> 1)) * OUTt + j];
      v1 = Wo[(((k0 + 1) & 1) * 128 + ((k0 + 1) >> 1)) * OUTt + j];
      v2 = Wo[(((k0 + 2) & 1) * 128 + ((k0 + 2) >> 1)) * OUTt + j];
      v3 = Wo[(((k0 + 3) & 1) * 128 + ((k0 + 3) >> 1)) * OUTt + j];
    }
    unsigned long long pk = (unsigned long long)pack2(v0, v1) |
                            ((unsigned long long)pack2(v2, v3) << 32);
    *(unsigned long long*)(&WoT[j * 256 + (k0 ^ ((j & 7) << 3))]) = pk;
  }

  // ---- branch weights: each wave owns h in [16w, 16w+16), K=128 (r6) ----
  Frag Wf[4];
  {
    const int h = 16 * w + l16;
    const int n = h >> 6, s = h & 63;
    #pragma unroll
    for (int ks = 0; ks < 4; ++ks) {
      #pragma unroll
      for (int j = 0; j < 8; ++j) {
        const int i = 32 * ks + 8 * lhi + j;
        Wf[ks].s[j] = (short)f2bf(Wb[(n * 128 + i) * 64 + s]);
      }
    }
  }

  // ---- scan params: waves 0,1; lane owns ch0 = 64w+lane and ch1 = ch0+128 ----
  float be0=0,om0=0,al0=0,oa0=0,bb0=0, be1=0,om1=0,al1=0,oa1=0,bb1=0;
  if (w < 2) {
    const int ch0 = 64 * w + lane;
    be0 = 1.f/(1.f+expf(-tau_n[ch0]));       om0 = 1.f - be0;
    al0 = 1.f/(1.f+expf(-tau_m[ch0]));       oa0 = 1.f - al0;
    bb0 = bb[ch0];
    be1 = 1.f/(1.f+expf(-tau_n[ch0+128]));   om1 = 1.f - be1;
    al1 = 1.f/(1.f+expf(-tau_m[ch0+128]));   oa1 = 1.f - al1;
    bb1 = bb[ch0+128];
  }
  const float bo_l = (l16 < OUTt) ? bo[l16] : 0.f;

  const float* xb   = x   + (size_t)b * Tt * INt;
  float*       outb = out + (size_t)b * Tt * OUTt;

  float c0 = 0.f, m0 = 0.f, c1 = 0.f, m1 = 0.f;   // scan state (waves 0,1)
  f32x4 dacc[4];                       // D accumulators, live across barriers
  f32x4 Q0, Q1;                        // stager prefetch (2 regs, split staging)

  #define BAR() do {                                                       \
    asm volatile("s_waitcnt lgkmcnt(0)" ::: "memory");                     \
    __builtin_amdgcn_s_barrier();                                          \
  } while (0)

  #define WAITVM(N) do {                                                   \
    asm volatile("s_waitcnt vmcnt(" #N ")" ::: "memory");                  \
    __builtin_amdgcn_sched_barrier(0);                                     \
  } while (0)

  // stager waves 8-15: rounds 0,1 of tile (asm-pinned, un-sinkable)
  #define ISSUE(TILE) do {                                                 \
    const float* _p = xb + (size_t)(TILE) * (TT * INt) + 4 * (size_t)sid;  \
    asm volatile("global_load_dwordx4 %0, %1, off" : "=&v"(Q0) : "v"(_p));        \
    asm volatile("global_load_dwordx4 %0, %1, off" : "=&v"(Q1) : "v"(_p + 2048)); \
  } while (0)

  // stage rounds 0,1 (from Q), issue+stage rounds 2,3; t = 16q + (sid>>5)
  #define STAGE(BUF, TILE) do {                                            \
    const int kb = 8 * (sid & 31);                                         \
    WAITVM(0);                                                             \
    {                                                                      \
      const int t = (sid >> 5);                                            \
      unsigned long long pk = (unsigned long long)pack2(Q0.x, Q0.y) |      \
            ((unsigned long long)pack2(Q0.z, Q0.w) << 32);                 \
      *(unsigned long long*)(&Xb[BUF][t * 256 + (kb ^ ((t & 7) << 4))]) = pk; \
    }                                                                      \
    {                                                                      \
      const int t = 16 + (sid >> 5);                                       \
      unsigned long long pk = (unsigned long long)pack2(Q1.x, Q1.y) |      \
            ((unsigned long long)pack2(Q1.z, Q1.w) << 32);                 \
      *(unsigned long long*)(&Xb[BUF][t * 256 + (kb ^ ((t & 7) << 4))]) = pk; \
    }                                                                      \
    const float* _p2 = xb + (size_t)(TILE) * (TT * INt) + 4 * (size_t)sid; \
    asm volatile("global_load_dwordx4 %0, %1, off" : "=&v"(Q0) : "v"(_p2 + 4096)); \
    asm volatile("global_load_dwordx4 %0, %1, off" : "=&v"(Q1) : "v"(_p2 + 6144)); \
    WAITVM(0);                                                             \
    {                                                                      \
      const int t = 32 + (sid >> 5);                                       \
      unsigned long long pk = (unsigned long long)pack2(Q0.x, Q0.y) |      \
            ((unsigned long long)pack2(Q0.z, Q0.w) << 32);                 \
      *(unsigned long long*)(&Xb[BUF][t * 256 + (kb ^ ((t & 7) << 4))]) = pk; \
    }                                                                      \
    {                                                                      \
      const int t = 48 + (sid >> 5);                                       \
      unsigned long long pk = (unsigned long long)pack2(Q1.x, Q1.y) |      \
            ((unsigned long long)pack2(Q1.z, Q1.w) << 32);                 \
      *(unsigned long long*)(&Xb[BUF][t * 256 + (kb ^ ((t & 7) << 4))]) = pk; \
    }                                                                      \
  } while (0)

  // wave w: D[t=0..64)[h=16w..16w+16), K=128 (r6-verbatim)
  #define GEMM(BUF) do {                                                   \
    _Pragma("unroll")                                                      \
    for (int tt = 0; tt < 4; ++tt) {                                       \
      dacc[tt] = f32x4{0.f, 0.f, 0.f, 0.f};                                \
      const int row = 16 * tt + l16;                                       \
      const int rs = row * 256, sw = (row & 7) << 4;                       \
      _Pragma("unroll")                                                    \
      for (int ks = 0; ks < 4; ++ks) {                                     \
        Frag a;                                                            \
        a.u = *(const u32x4*)(&Xb[BUF][rs + ((64 * ks + 16 * lhi) ^ sw)]); \
        dacc[tt] = __builtin_amdgcn_mfma_f32_16x16x32_bf16(                \
            a.b, Wf[ks].b, dacc[tt], 0, 0, 0);                             \
      }                                                                    \
    }                                                                      \
  } while (0)

  // dacc -> DfT[h][t] b128 (4 consecutive t), quad slot XOR (h&7) (r6-verbatim)
  #define WRITEDF() do {                                                   \
    const int h = 16 * w + l16;                                            \
    const int hb = h * 64, dsw = (h & 7) << 2;                             \
    _Pragma("unroll")                                                      \
    for (int tt = 0; tt < 4; ++tt)                                         \
      *(f32x4*)(&DfT[hb + ((16 * tt + 4 * lhi) ^ dsw)]) = dacc[tt];        \
  } while (0)

  // scan waves 0,1: 2 ch/lane (ch0, ch0+128), b128 row reads, packed-u32 Mb
  #define SCAN() do {                                                      \
    if (w < 2) {                                                           \
      const int ch0 = 64 * w + lane;                                       \
      const int hb0 = ch0 * 64;                                            \
      const int hb1 = hb0 + 128 * 64;                                      \
      const int ds0 = (ch0 & 7) << 2;   /* same for ch0+128 */             \
      const int p0  = 2 * ch0;                                             \
      _Pragma("unroll")                                                    \
      for (int q = 0; q < 16; ++q) {                                       \
        f32x4 dv0 = *(const f32x4*)(&DfT[hb0 + ((4 * q) ^ ds0)]);          \
        f32x4 dv1 = *(const f32x4*)(&DfT[hb1 + ((4 * q) ^ ds0)]);          \
        _Pragma("unroll")                                                  \
        for (int r = 0; r < 4; ++r) {                                      \
          const int t = 4 * q + r;                                         \
          const float d0 = dv0[r] + bb0;                                   \
          c0 = fmaf(be0, c0, om0 * d0);                                    \
          m0 = fmaf(al0, m0, oa0 * c0);                                    \
          const float d1 = dv1[r] + bb1;                                   \
          c1 = fmaf(be1, c1, om1 * d1);                                    \
          m1 = fmaf(al1, m1, oa1 * c1);                                    \
          *(unsigned int*)(&Mb[t * 256 + (p0 ^ ((t & 7) << 3))]) =         \
              pack2(m0, m1);                                               \
        }                                                                  \
      }                                                                    \
    }                                                                      \
  } while (0)

  // proj waves 4-7: rows [16(w-4),+16), full K=256 (permuted axis), r6-verbatim
  #define PROJ(TI) do {                                                    \
    const int tp = w - 4;                                                  \
    const int trow = 16 * tp + l16;                                        \
    const int mrb = trow * 256, msw = (trow & 7) << 3;                     \
    const int wrb = l16 * 256,  wsw = (l16 & 7) << 3;                      \
    f32x4 p = f32x4{0.f, 0.f, 0.f, 0.f};                                   \
    _Pragma("unroll")                                                      \
    for (int ks = 0; ks < 8; ++ks) {                                       \
      const int k0 = 32 * ks + 8 * lhi;                                    \
      Frag ma, wo;                                                         \
      ma.u = *(const u32x4*)(&Mb[mrb + (k0 ^ msw)]);                       \
      wo.u = *(const u32x4*)(&WoT[wrb + (k0 ^ wsw)]);                      \
      p = __builtin_amdgcn_mfma_f32_16x16x32_bf16(ma.b, wo.b, p, 0, 0, 0); \
    }                                                                      \
    if (l16 < OUTt) {                                                      \
      _Pragma("unroll")                                                    \
      for (int r = 0; r < 4; ++r) {                                        \
        const int t = 16 * tp + 4 * lhi + r;                               \
        outb[(size_t)((TI) * TT + t) * OUTt + l16] =                       \
            1.f / (1.f + __expf(-(p[r] + bo_l)));                          \
      }                                                                    \
    }                                                                      \
  } while (0)

  // ---------------- prologue ----------------
  if (w >= 8) {
    ISSUE(0); STAGE(0, 0);
    ISSUE(1); STAGE(1, 1);
  }
  BAR();
  GEMM(0);                             // dacc = D(0)

  // ---------------- pipeline (r6-verbatim schedule) ----------------
  // iter I: A{issue(I+2) rounds01, writeDfT(I), proj(I-1), GEMM(I+1)} B1
  //         B{scan(I), stage(I+2): wait+write01, issue23, wait+write23} B2
  #define ITER(I, DOPROJ, DOGEMM, DOIS) do {                               \
    if ((DOIS) && w >= 8) ISSUE((I) + 2);                                  \
    WRITEDF();                                                             \
    if ((DOPROJ) && w >= 4 && w < 8) PROJ((I) - 1);                        \
    if (DOGEMM) GEMM(((I) + 1) & 1);                                       \
    BAR();            /* B1 */                                             \
    SCAN();                                                                \
    if ((DOIS) && w >= 8) STAGE((I) & 1, (I) + 2);                         \
    BAR();            /* B2 */                                             \
  } while (0)

  ITER(0, 0, 1, 1);
  for (int I = 1; I <= 29; ++I) ITER(I, 1, 1, 1);
  ITER(30, 1, 1, 0);
  ITER(31, 1, 0, 0);
  if (w >= 4 && w < 8) PROJ(31);

  #undef ISSUE
  #undef STAGE
  #undef GEMM
  #undef WRITEDF
  #undef SCAN
  #undef PROJ
  #undef ITER
  #undef BAR
  #undef WAITVM
}

extern "C" void kernel_launch(void* const* d_in, const int* in_sizes, int n_in,
                              void* d_out, int out_size, void* d_ws, size_t ws_size,
                              hipStream_t stream) {
  const float* x     = (const float*)d_in[0];
  const float* Wb    = (const float*)d_in[1];
  const float* bb    = (const float*)d_in[2];
  const float* Wo    = (const float*)d_in[3];
  const float* bo    = (const float*)d_in[4];
  const float* tau_m = (const float*)d_in[5];
  const float* tau_n = (const float*)d_in[6];
  float* out = (float*)d_out;

  sfnn_fused<<<dim3(256), dim3(1024), 0, stream>>>(x, Wb, bb, Wo, bo, tau_m, tau_n, out);
}

// Round 14
// 102.024 us; speedup vs baseline: 1.4308x; 1.4308x over previous
//
#include <hip/hip_runtime.h>
#include <hip/hip_bf16.h>
#include <math.h>

#define DEVFN __device__ __forceinline__

typedef __attribute__((ext_vector_type(8))) __bf16 bf16x8;
typedef __attribute__((ext_vector_type(8))) short s16x8;
typedef __attribute__((ext_vector_type(4))) float f32x4;
typedef __attribute__((ext_vector_type(4))) unsigned int u32x4;

constexpr int Tt    = 2048;
constexpr int INt   = 128;
constexpr int Ht    = 256;
constexpr int OUTt  = 8;
constexpr int TT    = 64;           // time tile
constexpr int NTILE = 32;

union Frag {
  s16x8 s;
  bf16x8 b;
  u32x4 u;
};

DEVFN unsigned short f2bf(float f) {
  unsigned int u = __builtin_bit_cast(unsigned int, f);
  u += 0x7fffu + ((u >> 16) & 1u);   // round-to-nearest-even
  return (unsigned short)(u >> 16);
}

DEVFN unsigned int pack2(float lo, float hi) {
  return (unsigned int)f2bf(lo) | ((unsigned int)f2bf(hi) << 16);
}

__global__
__attribute__((amdgpu_flat_work_group_size(1024, 1024)))
void sfnn_fused(
    const float* __restrict__ x, const float* __restrict__ Wb,
    const float* __restrict__ bb, const float* __restrict__ Wo,
    const float* __restrict__ bo, const float* __restrict__ tau_m,
    const float* __restrict__ tau_n, float* __restrict__ out)
{
  const int b    = blockIdx.x;
  const int tid  = threadIdx.x;
  const int lane = tid & 63;
  const int w    = tid >> 6;          // wave id 0..15
  const int l16  = lane & 15;
  const int lhi  = lane >> 4;
  const int sid  = tid - 512;         // stager index (waves 8-15)

  // GEMM patch geometry: 16 waves x (32t x 32h) covering 64t x 256h
  const int tg = w >> 3;              // t-block: rows [32tg, 32tg+32)
  const int hg = w & 7;               // h-block: cols [32hg, 32hg+32)

  // LDS: 32KB Xb + 64KB DfT + 32KB Mb + 8KB WoT = 136KB  (r6 layout)
  __shared__ __align__(16) unsigned char  Xb[2][TT * 256];      // bf16 x, swizzled
  __shared__ __align__(16) float          DfT[Ht * TT];         // D^T f32 [h][t], swz
  __shared__ __align__(16) unsigned short Mb[TT * Ht];          // m bf16 [t][h], swz
  __shared__ __align__(16) unsigned short WoT[16 * Ht];         // Wo^T bf16 [j][k], swz

  // ---- stage WoT: [j][k] bf16, rows j>=8 zero (r6-verbatim) ----
  {
    const int j  = w;
    const int k0 = 4 * (tid & 63);
    float v0 = 0.f, v1 = 0.f, v2 = 0.f, v3 = 0.f;
    if (j < OUTt) {
      v0 = Wo[(k0 + 0) * OUTt + j]; v1 = Wo[(k0 + 1) * OUTt + j];
      v2 = Wo[(k0 + 2) * OUTt + j]; v3 = Wo[(k0 + 3) * OUTt + j];
    }
    unsigned long long pk = (unsigned long long)pack2(v0, v1) |
                            ((unsigned long long)pack2(v2, v3) << 32);
    *(unsigned long long*)(&WoT[j * 256 + (k0 ^ ((j & 7) << 3))]) = pk;
  }

  // ---- branch weights: wave owns h in [32hg, 32hg+32) (r2-verified) ----
  Frag Wf[2][4];                      // [16-col half][k-step] = 32 VGPRs
  #pragma unroll
  for (int nh = 0; nh < 2; ++nh) {
    const int h = 32 * hg + 16 * nh + l16;
    const int n = h >> 6, s = h & 63;
    #pragma unroll
    for (int ks = 0; ks < 4; ++ks) {
      #pragma unroll
      for (int j = 0; j < 8; ++j) {
        const int i = 32 * ks + 8 * lhi + j;
        Wf[nh][ks].s[j] = (short)f2bf(Wb[(n * 128 + i) * 64 + s]);
      }
    }
  }

  // ---- scan params: threads 0..255 only (channel = tid), guarded ----
  float beta = 0.f, alpha = 0.f, omb = 0.f, oma = 0.f, bbh = 0.f;
  if (tid < 256) {
    beta  = 1.f / (1.f + expf(-tau_n[tid]));
    alpha = 1.f / (1.f + expf(-tau_m[tid]));
    omb   = 1.f - beta;
    oma   = 1.f - alpha;
    bbh   = bb[tid];
  }
  float bo_l = 0.f;
  if (w >= 4 && w < 8) bo_l = (l16 < OUTt) ? bo[l16] : 0.f;

  const float* xb   = x   + (size_t)b * Tt * INt;
  float*       outb = out + (size_t)b * Tt * OUTt;

  float c_s = 0.f, m_s = 0.f;          // scan state (threads 0..255)
  f32x4 dacc[2][2];                    // [tt][nh], live across barriers
  f32x4 Q0, Q1;                        // stager prefetch (split staging)

  #define BAR() do {                                                       \
    asm volatile("s_waitcnt lgkmcnt(0)" ::: "memory");                     \
    __builtin_amdgcn_s_barrier();                                          \
  } while (0)

  #define WAITVM(N) do {                                                   \
    asm volatile("s_waitcnt vmcnt(" #N ")" ::: "memory");                  \
    __builtin_amdgcn_sched_barrier(0);                                     \
  } while (0)

  // stager waves 8-15: rounds 0,1 of tile (asm-pinned) -- r13-verified
  #define ISSUE(TILE) do {                                                 \
    const float* _p = xb + (size_t)(TILE) * (TT * INt) + 4 * (size_t)sid;  \
    asm volatile("global_load_dwordx4 %0, %1, off" : "=&v"(Q0) : "v"(_p));        \
    asm volatile("global_load_dwordx4 %0, %1, off" : "=&v"(Q1) : "v"(_p + 2048)); \
  } while (0)

  // stage rounds 0,1 (from Q), then issue+stage rounds 2,3 -- r13-verified
  #define STAGE(BUF, TILE) do {                                            \
    const int kb = 8 * (sid & 31);                                         \
    WAITVM(0);                                                             \
    {                                                                      \
      const int t = (sid >> 5);                                            \
      unsigned long long pk = (unsigned long long)pack2(Q0.x, Q0.y) |      \
            ((unsigned long long)pack2(Q0.z, Q0.w) << 32);                 \
      *(unsigned long long*)(&Xb[BUF][t * 256 + (kb ^ ((t & 7) << 4))]) = pk; \
    }                                                                      \
    {                                                                      \
      const int t = 16 + (sid >> 5);                                       \
      unsigned long long pk = (unsigned long long)pack2(Q1.x, Q1.y) |      \
            ((unsigned long long)pack2(Q1.z, Q1.w) << 32);                 \
      *(unsigned long long*)(&Xb[BUF][t * 256 + (kb ^ ((t & 7) << 4))]) = pk; \
    }                                                                      \
    const float* _p2 = xb + (size_t)(TILE) * (TT * INt) + 4 * (size_t)sid; \
    asm volatile("global_load_dwordx4 %0, %1, off" : "=&v"(Q0) : "v"(_p2 + 4096)); \
    asm volatile("global_load_dwordx4 %0, %1, off" : "=&v"(Q1) : "v"(_p2 + 6144)); \
    WAITVM(0);                                                             \
    {                                                                      \
      const int t = 32 + (sid >> 5);                                       \
      unsigned long long pk = (unsigned long long)pack2(Q0.x, Q0.y) |      \
            ((unsigned long long)pack2(Q0.z, Q0.w) << 32);                 \
      *(unsigned long long*)(&Xb[BUF][t * 256 + (kb ^ ((t & 7) << 4))]) = pk; \
    }                                                                      \
    {                                                                      \
      const int t = 48 + (sid >> 5);                                       \
      unsigned long long pk = (unsigned long long)pack2(Q1.x, Q1.y) |      \
            ((unsigned long long)pack2(Q1.z, Q1.w) << 32);                 \
      *(unsigned long long*)(&Xb[BUF][t * 256 + (kb ^ ((t & 7) << 4))]) = pk; \
    }                                                                      \
  } while (0)

  // GEMM: wave computes D[32tg..+32)[32hg..+32), K=128 (r2-verified patch)
  #define GEMM(BUF) do {                                                   \
    _Pragma("unroll")                                                      \
    for (int tt = 0; tt < 2; ++tt) {                                       \
      _Pragma("unroll")                                                    \
      for (int nh = 0; nh < 2; ++nh) dacc[tt][nh] = f32x4{0.f,0.f,0.f,0.f};\
      const int row = 32 * tg + 16 * tt + l16;                             \
      const int rs = row * 256, sw = (row & 7) << 4;                       \
      _Pragma("unroll")                                                    \
      for (int ks = 0; ks < 4; ++ks) {                                     \
        Frag a;                                                            \
        a.u = *(const u32x4*)(&Xb[BUF][rs + ((64 * ks + 16 * lhi) ^ sw)]); \
        _Pragma("unroll")                                                  \
        for (int nh = 0; nh < 2; ++nh)                                     \
          dacc[tt][nh] = __builtin_amdgcn_mfma_f32_16x16x32_bf16(          \
              a.b, Wf[nh][ks].b, dacc[tt][nh], 0, 0, 0);                   \
      }                                                                    \
    }                                                                      \
  } while (0)

  // dacc -> DfT[h][t] b128; t-quad qi = 8tg+4tt+lhi, slot (4qi)^((h&7)<<2)
  #define WRITEDF() do {                                                   \
    _Pragma("unroll")                                                      \
    for (int tt = 0; tt < 2; ++tt)                                         \
      _Pragma("unroll")                                                    \
      for (int nh = 0; nh < 2; ++nh) {                                     \
        const int h = 32 * hg + 16 * nh + l16;                             \
        const int qi = 8 * tg + 4 * tt + lhi;                              \
        *(f32x4*)(&DfT[h * 64 + ((4 * qi) ^ ((h & 7) << 2))]) =            \
            dacc[tt][nh];                                                  \
      }                                                                    \
  } while (0)

  // scan threads 0..255: contiguous-row b128 reads + serial EMA (r6-verbatim)
  #define SCAN() do {                                                      \
    if (tid < 256) {                                                       \
      const int hb = tid * 64, dsw = (tid & 7) << 2;                       \
      _Pragma("unroll")                                                    \
      for (int gg = 0; gg < 4; ++gg) {                                     \
        f32x4 dv[4];                                                       \
        _Pragma("unroll")                                                  \
        for (int q = 0; q < 4; ++q)                                        \
          dv[q] = *(const f32x4*)(&DfT[hb + ((16 * gg + 4 * q) ^ dsw)]);   \
        _Pragma("unroll")                                                  \
        for (int q = 0; q < 4; ++q)                                        \
          _Pragma("unroll")                                                \
          for (int r = 0; r < 4; ++r) {                                    \
            const int t = 16 * gg + 4 * q + r;                             \
            const float d = dv[q][r] + bbh;                                \
            c_s = fmaf(beta, c_s, omb * d);                                \
            m_s = fmaf(alpha, m_s, oma * c_s);                             \
            Mb[t * 256 + (tid ^ ((t & 7) << 3))] = f2bf(m_s);              \
          }                                                                \
      }                                                                    \
    }                                                                      \
  } while (0)

  // proj waves 4-7: rows [16(w-4),+16), full K=256 (r6-verbatim)
  #define PROJ(TI) do {                                                    \
    const int tp = w - 4;                                                  \
    const int trow = 16 * tp + l16;                                        \
    const int mrb = trow * 256, msw = (trow & 7) << 3;                     \
    const int wrb = l16 * 256,  wsw = (l16 & 7) << 3;                      \
    f32x4 p = f32x4{0.f, 0.f, 0.f, 0.f};                                   \
    _Pragma("unroll")                                                      \
    for (int ks = 0; ks < 8; ++ks) {                                       \
      const int k0 = 32 * ks + 8 * lhi;                                    \
      Frag ma, wo;                                                         \
      ma.u = *(const u32x4*)(&Mb[mrb + (k0 ^ msw)]);                       \
      wo.u = *(const u32x4*)(&WoT[wrb + (k0 ^ wsw)]);                      \
      p = __builtin_amdgcn_mfma_f32_16x16x32_bf16(ma.b, wo.b, p, 0, 0, 0); \
    }                                                                      \
    if (l16 < OUTt) {                                                      \
      _Pragma("unroll")                                                    \
      for (int r = 0; r < 4; ++r) {                                        \
        const int t = 16 * tp + 4 * lhi + r;                               \
        outb[(size_t)((TI) * TT + t) * OUTt + l16] =                       \
            1.f / (1.f + __expf(-(p[r] + bo_l)));                          \
      }                                                                    \
    }                                                                      \
  } while (0)

  // ---------------- prologue ----------------
  if (w >= 8) {
    ISSUE(0); STAGE(0, 0);
    ISSUE(1); STAGE(1, 1);
  }
  BAR();
  GEMM(0);                             // dacc = D(0)

  // ---------------- pipeline (r6-verbatim schedule) ----------------
  // iter I: A{issue(I+2) rounds01, writeDfT(I), proj(I-1), GEMM(I+1)} B1
  //         B{scan(I), stage(I+2) split} B2
  #define ITER(I, DOPROJ, DOGEMM, DOIS) do {                               \
    if ((DOIS) && w >= 8) ISSUE((I) + 2);                                  \
    WRITEDF();                                                             \
    if ((DOPROJ) && w >= 4 && w < 8) PROJ((I) - 1);                        \
    if (DOGEMM) GEMM(((I) + 1) & 1);                                       \
    BAR();            /* B1 */                                             \
    SCAN();                                                                \
    if ((DOIS) && w >= 8) STAGE((I) & 1, (I) + 2);                         \
    BAR();            /* B2 */                                             \
  } while (0)

  ITER(0, 0, 1, 1);
  for (int I = 1; I <= 29; ++I) ITER(I, 1, 1, 1);
  ITER(30, 1, 1, 0);
  ITER(31, 1, 0, 0);
  if (w >= 4 && w < 8) PROJ(31);

  #undef ISSUE
  #undef STAGE
  #undef GEMM
  #undef WRITEDF
  #undef SCAN
  #undef PROJ
  #undef ITER
  #undef BAR
  #undef WAITVM
}

extern "C" void kernel_launch(void* const* d_in, const int* in_sizes, int n_in,
                              void* d_out, int out_size, void* d_ws, size_t ws_size,
                              hipStream_t stream) {
  const float* x     = (const float*)d_in[0];
  const float* Wb    = (const float*)d_in[1];
  const float* bb    = (const float*)d_in[2];
  const float* Wo    = (const float*)d_in[3];
  const float* bo    = (const float*)d_in[4];
  const float* tau_m = (const float*)d_in[5];
  const float* tau_n = (const float*)d_in[6];
  float* out = (float*)d_out;

  sfnn_fused<<<dim3(256), dim3(1024), 0, stream>>>(x, Wb, bb, Wo, bo, tau_m, tau_n, out);
}

// Round 16
// 96.593 us; speedup vs baseline: 1.5112x; 1.0562x over previous
//
#include <hip/hip_runtime.h>
#include <hip/hip_bf16.h>
#include <math.h>

#define DEVFN __device__ __forceinline__

typedef __attribute__((ext_vector_type(8))) __bf16 bf16x8;
typedef __attribute__((ext_vector_type(8))) short s16x8;
typedef __attribute__((ext_vector_type(4))) float f32x4;
typedef __attribute__((ext_vector_type(4))) unsigned int u32x4;

constexpr int Tt    = 2048;
constexpr int INt   = 128;
constexpr int Ht    = 256;
constexpr int OUTt  = 8;
constexpr int TT    = 32;           // time tile
constexpr int NTILE = 64;

union Frag {
  s16x8 s;
  bf16x8 b;
  u32x4 u;
};

DEVFN unsigned short f2bf(float f) {
  unsigned int u = __builtin_bit_cast(unsigned int, f);
  u += 0x7fffu + ((u >> 16) & 1u);   // round-to-nearest-even
  return (unsigned short)(u >> 16);
}

DEVFN unsigned int pack2(float lo, float hi) {
  return (unsigned int)f2bf(lo) | ((unsigned int)f2bf(hi) << 16);
}

__global__
__attribute__((amdgpu_flat_work_group_size(1024, 1024)))
void sfnn_fused(
    const float* __restrict__ x, const float* __restrict__ Wb,
    const float* __restrict__ bb, const float* __restrict__ Wo,
    const float* __restrict__ bo, const float* __restrict__ tau_m,
    const float* __restrict__ tau_n, float* __restrict__ out)
{
  const int b    = blockIdx.x;
  const int tid  = threadIdx.x;
  const int lane = tid & 63;
  const int w    = tid >> 6;          // wave id 0..15
  const int l16  = lane & 15;
  const int lhi  = lane >> 4;
  const int sid  = tid - 512;         // stager index (waves 8-15)

  // LDS: 24KB Xb[3] + 64KB DfT[2] + 32KB Mb[2] + 8KB WoT = 128KB
  __shared__ __align__(16) unsigned char  Xb[3][TT * 256];      // bf16 x, swizzled
  __shared__ __align__(16) float          DfT[2][Ht * TT];      // D^T f32 [h][t], swz
  __shared__ __align__(16) unsigned short Mb[2][TT * Ht];       // m bf16 [t][h], swz
  __shared__ __align__(16) unsigned short WoT[16 * Ht];         // Wo^T bf16 [j][k], swz

  // ---- stage WoT: [j][k] bf16, rows j>=8 zero (r6-verbatim) ----
  {
    const int j  = w;
    const int k0 = 4 * (tid & 63);
    float v0 = 0.f, v1 = 0.f, v2 = 0.f, v3 = 0.f;
    if (j < OUTt) {
      v0 = Wo[(k0 + 0) * OUTt + j]; v1 = Wo[(k0 + 1) * OUTt + j];
      v2 = Wo[(k0 + 2) * OUTt + j]; v3 = Wo[(k0 + 3) * OUTt + j];
    }
    unsigned long long pk = (unsigned long long)pack2(v0, v1) |
                            ((unsigned long long)pack2(v2, v3) << 32);
    *(unsigned long long*)(&WoT[j * 256 + (k0 ^ ((j & 7) << 3))]) = pk;
  }

  // ---- branch weights: wave owns h in [16w, 16w+16), K=128 (16 regs) ----
  Frag Wf[4];
  {
    const int h = 16 * w + l16;
    const int n = h >> 6, s = h & 63;
    #pragma unroll
    for (int ks = 0; ks < 4; ++ks) {
      #pragma unroll
      for (int j = 0; j < 8; ++j) {
        const int i = 32 * ks + 8 * lhi + j;
        Wf[ks].s[j] = (short)f2bf(Wb[(n * 128 + i) * 64 + s]);
      }
    }
  }

  // ---- scan params: threads 0..255 (channel = tid), guarded ----
  float beta = 0.f, alpha = 0.f, omb = 0.f, oma = 0.f, bbh = 0.f;
  if (tid < 256) {
    beta  = 1.f / (1.f + expf(-tau_n[tid]));
    alpha = 1.f / (1.f + expf(-tau_m[tid]));
    omb   = 1.f - beta;
    oma   = 1.f - alpha;
    bbh   = bb[tid];
  }
  float bo_l = 0.f;
  if (w == 4 || w == 5) bo_l = (l16 < OUTt) ? bo[l16] : 0.f;

  const float* xb   = x   + (size_t)b * Tt * INt;
  float*       outb = out + (size_t)b * Tt * OUTt;

  float c_s = 0.f, m_s = 0.f;          // scan state (threads 0..255)
  f32x4 dacc[2];                       // [tt] (within-phase only)
  f32x4 QA0, QA1, QB0, QB1;            // TWO stager prefetch sets (hazard fix)

  #define BAR() do {                                                       \
    asm volatile("s_waitcnt lgkmcnt(0)" ::: "memory");                     \
    __builtin_amdgcn_s_barrier();                                          \
  } while (0)

  #define WAITVM(N) do {                                                   \
    asm volatile("s_waitcnt vmcnt(" #N ")" ::: "memory");                  \
    __builtin_amdgcn_sched_barrier(0);                                     \
  } while (0)

  // stager waves 8-15: tile = 4096 floats; 2 x 16B asm-pinned loads
  #define ISSUE(TILE, Q0, Q1) do {                                         \
    const float* _p = xb + (size_t)(TILE) * (TT * INt) + 4 * (size_t)sid;  \
    asm volatile("global_load_dwordx4 %0, %1, off" : "=&v"(Q0) : "v"(_p));        \
    asm volatile("global_load_dwordx4 %0, %1, off" : "=&v"(Q1) : "v"(_p + 2048)); \
  } while (0)

  // write staged rounds: float f = 2048q + 4sid -> t = 16q + (sid>>5)
  #define STAGEWR(BUF, Q0, Q1) do {                                        \
    const int kb = 8 * (sid & 31);                                         \
    {                                                                      \
      const int t = (sid >> 5);                                            \
      unsigned long long pk = (unsigned long long)pack2(Q0.x, Q0.y) |      \
            ((unsigned long long)pack2(Q0.z, Q0.w) << 32);                 \
      *(unsigned long long*)(&Xb[BUF][t * 256 + (kb ^ ((t & 7) << 4))]) = pk; \
    }                                                                      \
    {                                                                      \
      const int t = 16 + (sid >> 5);                                       \
      unsigned long long pk = (unsigned long long)pack2(Q1.x, Q1.y) |      \
            ((unsigned long long)pack2(Q1.z, Q1.w) << 32);                 \
      *(unsigned long long*)(&Xb[BUF][t * 256 + (kb ^ ((t & 7) << 4))]) = pk; \
    }                                                                      \
  } while (0)

  // GEMM: wave computes D[0..32)[16w..+16), K=128; 8 b128 reads + 8 MFMA
  #define GEMM(BUF) do {                                                   \
    _Pragma("unroll")                                                      \
    for (int tt = 0; tt < 2; ++tt) {                                       \
      dacc[tt] = f32x4{0.f, 0.f, 0.f, 0.f};                                \
      const int row = 16 * tt + l16;                                       \
      const int rs = row * 256, sw = (row & 7) << 4;                       \
      _Pragma("unroll")                                                    \
      for (int ks = 0; ks < 4; ++ks) {                                     \
        Frag a;                                                            \
        a.u = *(const u32x4*)(&Xb[BUF][rs + ((64 * ks + 16 * lhi) ^ sw)]); \
        dacc[tt] = __builtin_amdgcn_mfma_f32_16x16x32_bf16(                \
            a.b, Wf[ks].b, dacc[tt], 0, 0, 0);                             \
      }                                                                    \
    }                                                                      \
  } while (0)

  // dacc -> DfT[h][t]: rows 128B (32 f32); t-quad qi = 4tt+lhi, slot qi^(h&7)
  #define WRITEDF(BUF) do {                                                \
    const int h = 16 * w + l16;                                            \
    _Pragma("unroll")                                                      \
    for (int tt = 0; tt < 2; ++tt) {                                       \
      const int qi = 4 * tt + lhi;                                         \
      *(f32x4*)(&DfT[BUF][h * 32 + ((qi ^ (h & 7)) << 2)]) = dacc[tt];     \
    }                                                                      \
  } while (0)

  // scan threads 0..255: own-row b128 reads (slot q^h7) + serial EMA + Mb b16
  #define SCAN(BUF) do {                                                   \
    if (tid < 256) {                                                       \
      const int hb = tid * 32, h7 = tid & 7;                               \
      _Pragma("unroll")                                                    \
      for (int g = 0; g < 2; ++g) {                                        \
        f32x4 dv[4];                                                       \
        _Pragma("unroll")                                                  \
        for (int q = 0; q < 4; ++q)                                        \
          dv[q] = *(const f32x4*)(&DfT[BUF][hb + (((4 * g + q) ^ h7) << 2)]); \
        _Pragma("unroll")                                                  \
        for (int q = 0; q < 4; ++q)                                        \
          _Pragma("unroll")                                                \
          for (int r = 0; r < 4; ++r) {                                    \
            const int t = 16 * g + 4 * q + r;                              \
            const float d = dv[q][r] + bbh;                                \
            c_s = fmaf(beta, c_s, omb * d);                                \
            m_s = fmaf(alpha, m_s, oma * c_s);                             \
            Mb[BUF][t * 256 + (tid ^ ((t & 7) << 3))] = f2bf(m_s);         \
          }                                                                \
      }                                                                    \
    }                                                                      \
  } while (0)

  // proj waves 4,5: rows [16(w-4),+16), full K=256 (r6-verbatim)
  #define PROJ(TI, BUF) do {                                               \
    const int tp = w - 4;                                                  \
    const int trow = 16 * tp + l16;                                        \
    const int mrb = trow * 256, msw = (trow & 7) << 3;                     \
    const int wrb = l16 * 256,  wsw = (l16 & 7) << 3;                      \
    f32x4 p = f32x4{0.f, 0.f, 0.f, 0.f};                                   \
    _Pragma("unroll")                                                      \
    for (int ks = 0; ks < 8; ++ks) {                                       \
      const int k0 = 32 * ks + 8 * lhi;                                    \
      Frag ma, wo;                                                         \
      ma.u = *(const u32x4*)(&Mb[BUF][mrb + (k0 ^ msw)]);                  \
      wo.u = *(const u32x4*)(&WoT[wrb + (k0 ^ wsw)]);                      \
      p = __builtin_amdgcn_mfma_f32_16x16x32_bf16(ma.b, wo.b, p, 0, 0, 0); \
    }                                                                      \
    if (l16 < OUTt) {                                                      \
      _Pragma("unroll")                                                    \
      for (int r = 0; r < 4; ++r) {                                        \
        const int t = 16 * tp + 4 * lhi + r;                               \
        outb[(size_t)((TI) * TT + t) * OUTt + l16] =                       \
            1.f / (1.f + __expf(-(p[r] + bo_l)));                          \
      }                                                                    \
    }                                                                      \
  } while (0)

  // ---- single-phase iteration, 1 barrier; QA/QB alternate (hazard-free) ----
  // even iter I: ISSUE(I+2)->A | GEMM(I) | SCAN(I-1) | PROJ(I-2)
  //              | WAITVM(2) retires B(tile I+1) | STAGEWR(B) | BAR
  #define ITER_EV(I, DOG, DOS, DOP, DOISS, DOSTG, WN) do {                 \
    if ((DOISS) && w >= 8) ISSUE((I) + 2, QA0, QA1);                       \
    if (DOG) { GEMM((I) % 3); WRITEDF((I) & 1); }                          \
    if ((DOS) && w < 4) SCAN(((I) - 1) & 1);                               \
    if ((DOP) && (w == 4 || w == 5)) PROJ((I) - 2, (I) & 1);               \
    if ((DOSTG) && w >= 8) { WAITVM(WN); STAGEWR(((I) + 1) % 3, QB0, QB1); } \
    BAR();                                                                 \
  } while (0)

  #define ITER_OD(I, DOG, DOS, DOP, DOISS, DOSTG, WN) do {                 \
    if ((DOISS) && w >= 8) ISSUE((I) + 2, QB0, QB1);                       \
    if (DOG) { GEMM((I) % 3); WRITEDF((I) & 1); }                          \
    if ((DOS) && w < 4) SCAN(((I) - 1) & 1);                               \
    if ((DOP) && (w == 4 || w == 5)) PROJ((I) - 2, (I) & 1);               \
    if ((DOSTG) && w >= 8) { WAITVM(WN); STAGEWR(((I) + 1) % 3, QA0, QA1); } \
    BAR();                                                                 \
  } while (0)

  // ---------------- prologue: stage tile 0 (A), issue tile 1 (B) ----------
  if (w >= 8) {
    ISSUE(0, QA0, QA1);
    WAITVM(0);
    STAGEWR(0, QA0, QA1);
    ISSUE(1, QB0, QB1);                // in flight across barrier
  }
  BAR();

  // ---------------- pipeline: I = 0..65 ----------------
  ITER_EV(0, 1, 0, 0, 1, 1, 2);        // issue 2->A, stage 1 (B)
  ITER_OD(1, 1, 1, 0, 1, 1, 2);        // issue 3->B, stage 2 (A)
  for (int jj = 1; jj <= 30; ++jj) {
    ITER_EV(2 * jj,     1, 1, 1, 1, 1, 2);
    ITER_OD(2 * jj + 1, 1, 1, 1, 1, 1, 2);
  }
  ITER_EV(62, 1, 1, 1, 0, 1, 0);       // drain, stage 63 (B)
  ITER_OD(63, 1, 1, 1, 0, 0, 0);
  ITER_EV(64, 0, 1, 1, 0, 0, 0);       // SCAN(63), PROJ(62)
  ITER_OD(65, 0, 0, 1, 0, 0, 0);       // PROJ(63)

  #undef ISSUE
  #undef STAGEWR
  #undef GEMM
  #undef WRITEDF
  #undef SCAN
  #undef PROJ
  #undef ITER_EV
  #undef ITER_OD
  #undef BAR
  #undef WAITVM
}

extern "C" void kernel_launch(void* const* d_in, const int* in_sizes, int n_in,
                              void* d_out, int out_size, void* d_ws, size_t ws_size,
                              hipStream_t stream) {
  const float* x     = (const float*)d_in[0];
  const float* Wb    = (const float*)d_in[1];
  const float* bb    = (const float*)d_in[2];
  const float* Wo    = (const float*)d_in[3];
  const float* bo    = (const float*)d_in[4];
  const float* tau_m = (const float*)d_in[5];
  const float* tau_n = (const float*)d_in[6];
  float* out = (float*)d_out;

  sfnn_fused<<<dim3(256), dim3(1024), 0, stream>>>(x, Wb, bb, Wo, bo, tau_m, tau_n, out);
}

// Round 17
// 92.363 us; speedup vs baseline: 1.5804x; 1.0458x over previous
//
#include <hip/hip_runtime.h>
#include <hip/hip_bf16.h>
#include <math.h>

#define DEVFN __device__ __forceinline__

typedef __attribute__((ext_vector_type(8))) __bf16 bf16x8;
typedef __attribute__((ext_vector_type(8))) short s16x8;
typedef __attribute__((ext_vector_type(4))) float f32x4;
typedef __attribute__((ext_vector_type(4))) unsigned int u32x4;

constexpr int Tt    = 2048;
constexpr int INt   = 128;
constexpr int Ht    = 256;
constexpr int OUTt  = 8;
constexpr int TT    = 32;           // time tile
constexpr int NTILE = 64;

union Frag {
  s16x8 s;
  bf16x8 b;
  u32x4 u;
};

DEVFN unsigned short f2bf(float f) {
  unsigned int u = __builtin_bit_cast(unsigned int, f);
  u += 0x7fffu + ((u >> 16) & 1u);   // round-to-nearest-even
  return (unsigned short)(u >> 16);
}

DEVFN unsigned int pack2(float lo, float hi) {
  return (unsigned int)f2bf(lo) | ((unsigned int)f2bf(hi) << 16);
}

__global__
__attribute__((amdgpu_flat_work_group_size(1024, 1024)))
void sfnn_fused(
    const float* __restrict__ x, const float* __restrict__ Wb,
    const float* __restrict__ bb, const float* __restrict__ Wo,
    const float* __restrict__ bo, const float* __restrict__ tau_m,
    const float* __restrict__ tau_n, float* __restrict__ out)
{
  const int b    = blockIdx.x;
  const int tid  = threadIdx.x;
  const int lane = tid & 63;
  const int w    = tid >> 6;          // wave id 0..15
  const int l16  = lane & 15;
  const int lhi  = lane >> 4;
  const int sid  = tid - 512;         // stager index (waves 8-15)

  // GEMM decomposition: 16 waves x (16t x 32h) covering 32t x 256h
  const int tg = w >> 3;              // t-half: rows [16tg, 16tg+16)
  const int hg = w & 7;               // h-strip: cols [32hg, 32hg+32)

  // LDS: 24KB Xb[3] + 64KB DfT[2] + 32KB Mb[2] + 8KB WoT = 128KB
  __shared__ __align__(16) unsigned char  Xb[3][TT * 256];      // bf16 x, swizzled
  __shared__ __align__(16) float          DfT[2][Ht * TT];      // D^T f32 [h][t], swz
  __shared__ __align__(16) unsigned short Mb[2][TT * Ht];       // m bf16 [t][h], swz
  __shared__ __align__(16) unsigned short WoT[16 * Ht];         // Wo^T bf16 [j][k], swz

  // ---- stage WoT: [j][k] bf16, rows j>=8 zero (r6-verbatim) ----
  {
    const int j  = w;
    const int k0 = 4 * (tid & 63);
    float v0 = 0.f, v1 = 0.f, v2 = 0.f, v3 = 0.f;
    if (j < OUTt) {
      v0 = Wo[(k0 + 0) * OUTt + j]; v1 = Wo[(k0 + 1) * OUTt + j];
      v2 = Wo[(k0 + 2) * OUTt + j]; v3 = Wo[(k0 + 3) * OUTt + j];
    }
    unsigned long long pk = (unsigned long long)pack2(v0, v1) |
                            ((unsigned long long)pack2(v2, v3) << 32);
    *(unsigned long long*)(&WoT[j * 256 + (k0 ^ ((j & 7) << 3))]) = pk;
  }

  // ---- branch weights: wave owns h in [32hg, 32hg+32) (r14-verified) ----
  Frag Wf[2][4];                      // [16-col half][k-step] = 32 VGPRs
  #pragma unroll
  for (int nh = 0; nh < 2; ++nh) {
    const int h = 32 * hg + 16 * nh + l16;
    const int n = h >> 6, s = h & 63;
    #pragma unroll
    for (int ks = 0; ks < 4; ++ks) {
      #pragma unroll
      for (int j = 0; j < 8; ++j) {
        const int i = 32 * ks + 8 * lhi + j;
        Wf[nh][ks].s[j] = (short)f2bf(Wb[(n * 128 + i) * 64 + s]);
      }
    }
  }

  // ---- scan params: threads 0..255 (channel = tid), guarded ----
  float beta = 0.f, alpha = 0.f, omb = 0.f, oma = 0.f, bbh = 0.f;
  if (tid < 256) {
    beta  = 1.f / (1.f + expf(-tau_n[tid]));
    alpha = 1.f / (1.f + expf(-tau_m[tid]));
    omb   = 1.f - beta;
    oma   = 1.f - alpha;
    bbh   = bb[tid];
  }
  float bo_l = 0.f;
  if (w == 4 || w == 5) bo_l = (l16 < OUTt) ? bo[l16] : 0.f;

  const float* xb   = x   + (size_t)b * Tt * INt;
  float*       outb = out + (size_t)b * Tt * OUTt;

  float c_s = 0.f, m_s = 0.f;          // scan state (threads 0..255)
  f32x4 dacc[2];                       // [nh] (within-phase only)
  f32x4 QA0, QA1, QB0, QB1;            // TWO stager prefetch sets (hazard-free)

  #define BAR() do {                                                       \
    asm volatile("s_waitcnt lgkmcnt(0)" ::: "memory");                     \
    __builtin_amdgcn_s_barrier();                                          \
  } while (0)

  #define WAITVM(N) do {                                                   \
    asm volatile("s_waitcnt vmcnt(" #N ")" ::: "memory");                  \
    __builtin_amdgcn_sched_barrier(0);                                     \
  } while (0)

  // stager waves 8-15: tile = 4096 floats; 2 x 16B asm-pinned loads
  #define ISSUE(TILE, Q0, Q1) do {                                         \
    const float* _p = xb + (size_t)(TILE) * (TT * INt) + 4 * (size_t)sid;  \
    asm volatile("global_load_dwordx4 %0, %1, off" : "=&v"(Q0) : "v"(_p));        \
    asm volatile("global_load_dwordx4 %0, %1, off" : "=&v"(Q1) : "v"(_p + 2048)); \
  } while (0)

  // write staged rounds: float f = 2048q + 4sid -> t = 16q + (sid>>5)
  #define STAGEWR(BUF, Q0, Q1) do {                                        \
    const int kb = 8 * (sid & 31);                                         \
    {                                                                      \
      const int t = (sid >> 5);                                            \
      unsigned long long pk = (unsigned long long)pack2(Q0.x, Q0.y) |      \
            ((unsigned long long)pack2(Q0.z, Q0.w) << 32);                 \
      *(unsigned long long*)(&Xb[BUF][t * 256 + (kb ^ ((t & 7) << 4))]) = pk; \
    }                                                                      \
    {                                                                      \
      const int t = 16 + (sid >> 5);                                       \
      unsigned long long pk = (unsigned long long)pack2(Q1.x, Q1.y) |      \
            ((unsigned long long)pack2(Q1.z, Q1.w) << 32);                 \
      *(unsigned long long*)(&Xb[BUF][t * 256 + (kb ^ ((t & 7) << 4))]) = pk; \
    }                                                                      \
  } while (0)

  // GEMM: wave computes D[16tg..+16)[32hg..+32), K=128; 4 b128 reads + 8 MFMA
  #define GEMM(BUF) do {                                                   \
    dacc[0] = f32x4{0.f, 0.f, 0.f, 0.f};                                   \
    dacc[1] = f32x4{0.f, 0.f, 0.f, 0.f};                                   \
    const int row = 16 * tg + l16;                                         \
    const int rs = row * 256, sw = (row & 7) << 4;                         \
    _Pragma("unroll")                                                      \
    for (int ks = 0; ks < 4; ++ks) {                                       \
      Frag a;                                                              \
      a.u = *(const u32x4*)(&Xb[BUF][rs + ((64 * ks + 16 * lhi) ^ sw)]);   \
      dacc[0] = __builtin_amdgcn_mfma_f32_16x16x32_bf16(                   \
          a.b, Wf[0][ks].b, dacc[0], 0, 0, 0);                             \
      dacc[1] = __builtin_amdgcn_mfma_f32_16x16x32_bf16(                   \
          a.b, Wf[1][ks].b, dacc[1], 0, 0, 0);                             \
    }                                                                      \
  } while (0)

  // dacc -> DfT[h][t]: rows 128B (32 f32); t-quad qi = 4tg+lhi, slot qi^(h&7)
  #define WRITEDF(BUF) do {                                                \
    const int qi = 4 * tg + lhi;                                           \
    _Pragma("unroll")                                                      \
    for (int nh = 0; nh < 2; ++nh) {                                       \
      const int h = 32 * hg + 16 * nh + l16;                               \
      *(f32x4*)(&DfT[BUF][h * 32 + ((qi ^ (h & 7)) << 2)]) = dacc[nh];     \
    }                                                                      \
  } while (0)

  // scan threads 0..255: own-row b128 reads (slot q^h7) + serial EMA + Mb b16
  #define SCAN(BUF) do {                                                   \
    if (tid < 256) {                                                       \
      const int hb = tid * 32, h7 = tid & 7;                               \
      _Pragma("unroll")                                                    \
      for (int g = 0; g < 2; ++g) {                                        \
        f32x4 dv[4];                                                       \
        _Pragma("unroll")                                                  \
        for (int q = 0; q < 4; ++q)                                        \
          dv[q] = *(const f32x4*)(&DfT[BUF][hb + (((4 * g + q) ^ h7) << 2)]); \
        _Pragma("unroll")                                                  \
        for (int q = 0; q < 4; ++q)                                        \
          _Pragma("unroll")                                                \
          for (int r = 0; r < 4; ++r) {                                    \
            const int t = 16 * g + 4 * q + r;                              \
            const float d = dv[q][r] + bbh;                                \
            c_s = fmaf(beta, c_s, omb * d);                                \
            m_s = fmaf(alpha, m_s, oma * c_s);                             \
            Mb[BUF][t * 256 + (tid ^ ((t & 7) << 3))] = f2bf(m_s);         \
          }                                                                \
      }                                                                    \
    }                                                                      \
  } while (0)

  // proj waves 4,5: rows [16(w-4),+16), full K=256 (r6-verbatim)
  #define PROJ(TI, BUF) do {                                               \
    const int tp = w - 4;                                                  \
    const int trow = 16 * tp + l16;                                        \
    const int mrb = trow * 256, msw = (trow & 7) << 3;                     \
    const int wrb = l16 * 256,  wsw = (l16 & 7) << 3;                      \
    f32x4 p = f32x4{0.f, 0.f, 0.f, 0.f};                                   \
    _Pragma("unroll")                                                      \
    for (int ks = 0; ks < 8; ++ks) {                                       \
      const int k0 = 32 * ks + 8 * lhi;                                    \
      Frag ma, wo;                                                         \
      ma.u = *(const u32x4*)(&Mb[BUF][mrb + (k0 ^ msw)]);                  \
      wo.u = *(const u32x4*)(&WoT[wrb + (k0 ^ wsw)]);                      \
      p = __builtin_amdgcn_mfma_f32_16x16x32_bf16(ma.b, wo.b, p, 0, 0, 0); \
    }                                                                      \
    if (l16 < OUTt) {                                                      \
      _Pragma("unroll")                                                    \
      for (int r = 0; r < 4; ++r) {                                        \
        const int t = 16 * tp + 4 * lhi + r;                               \
        outb[(size_t)((TI) * TT + t) * OUTt + l16] =                       \
            1.f / (1.f + __expf(-(p[r] + bo_l)));                          \
      }                                                                    \
    }                                                                      \
  } while (0)

  // ---- single-phase iteration, 1 barrier; QA/QB alternate (hazard-free) ----
  #define ITER_EV(I, DOG, DOS, DOP, DOISS, DOSTG, WN) do {                 \
    if ((DOISS) && w >= 8) ISSUE((I) + 2, QA0, QA1);                       \
    if (DOG) { GEMM((I) % 3); WRITEDF((I) & 1); }                          \
    if ((DOS) && w < 4) SCAN(((I) - 1) & 1);                               \
    if ((DOP) && (w == 4 || w == 5)) PROJ((I) - 2, (I) & 1);               \
    if ((DOSTG) && w >= 8) { WAITVM(WN); STAGEWR(((I) + 1) % 3, QB0, QB1); } \
    BAR();                                                                 \
  } while (0)

  #define ITER_OD(I, DOG, DOS, DOP, DOISS, DOSTG, WN) do {                 \
    if ((DOISS) && w >= 8) ISSUE((I) + 2, QB0, QB1);                       \
    if (DOG) { GEMM((I) % 3); WRITEDF((I) & 1); }                          \
    if ((DOS) && w < 4) SCAN(((I) - 1) & 1);                               \
    if ((DOP) && (w == 4 || w == 5)) PROJ((I) - 2, (I) & 1);               \
    if ((DOSTG) && w >= 8) { WAITVM(WN); STAGEWR(((I) + 1) % 3, QA0, QA1); } \
    BAR();                                                                 \
  } while (0)

  // ---------------- prologue: stage tile 0 (A), issue tile 1 (B) ----------
  if (w >= 8) {
    ISSUE(0, QA0, QA1);
    WAITVM(0);
    STAGEWR(0, QA0, QA1);
    ISSUE(1, QB0, QB1);                // in flight across barrier
  }
  BAR();

  // ---------------- pipeline: I = 0..65 ----------------
  ITER_EV(0, 1, 0, 0, 1, 1, 2);        // issue 2->A, stage 1 (B)
  ITER_OD(1, 1, 1, 0, 1, 1, 2);        // issue 3->B, stage 2 (A)
  for (int jj = 1; jj <= 30; ++jj) {
    ITER_EV(2 * jj,     1, 1, 1, 1, 1, 2);
    ITER_OD(2 * jj + 1, 1, 1, 1, 1, 1, 2);
  }
  ITER_EV(62, 1, 1, 1, 0, 1, 0);       // drain, stage 63 (B)
  ITER_OD(63, 1, 1, 1, 0, 0, 0);
  ITER_EV(64, 0, 1, 1, 0, 0, 0);       // SCAN(63), PROJ(62)
  ITER_OD(65, 0, 0, 1, 0, 0, 0);       // PROJ(63)

  #undef ISSUE
  #undef STAGEWR
  #undef GEMM
  #undef WRITEDF
  #undef SCAN
  #undef PROJ
  #undef ITER_EV
  #undef ITER_OD
  #undef BAR
  #undef WAITVM
}

extern "C" void kernel_launch(void* const* d_in, const int* in_sizes, int n_in,
                              void* d_out, int out_size, void* d_ws, size_t ws_size,
                              hipStream_t stream) {
  const float* x     = (const float*)d_in[0];
  const float* Wb    = (const float*)d_in[1];
  const float* bb    = (const float*)d_in[2];
  const float* Wo    = (const float*)d_in[3];
  const float* bo    = (const float*)d_in[4];
  const float* tau_m = (const float*)d_in[5];
  const float* tau_n = (const float*)d_in[6];
  float* out = (float*)d_out;

  sfnn_fused<<<dim3(256), dim3(1024), 0, stream>>>(x, Wb, bb, Wo, bo, tau_m, tau_n, out);
}